// Round 23
// baseline (5535.130 us; speedup 1.0000x reference)
//
#include <hip/hip_runtime.h>
#include <math.h>

// ---- problem dims ----
#define TN 64
#define BN 32
#define EPSF 1e-6f

// ---- workspace layout (floats) ----
constexpr long OFF_H     = 0;                       // 65 * 32*1024
constexpr long OFF_RV    = OFF_H    + 65L*32768;    // 65 * 32*256
constexpr long OFF_S     = OFF_RV   + 65L*8192;     // 32768
constexpr long OFF_RW    = OFF_S    + 32768;        // B*N*HD = 16384
constexpr long OFF_WW    = OFF_RW   + 16384;        // B*N
constexpr long OFF_U     = OFF_WW   + 4096;
constexpr long OFF_P     = OFF_U    + 4096;
constexpr long OFF_MEM   = OFF_P    + 4096;         // B*N*WD = 262144
constexpr long OFF_LINKS = OFF_MEM  + 262144;       // B*N*N = 524288
constexpr long OFF_PROJ  = OFF_LINKS+ 524288;       // B*512 (471 used)
constexpr long OFF_SRC   = OFF_PROJ + 16384;        // 2048 ints
constexpr long OFF_XBF   = OFF_SRC  + 2048;         // 32*1800 bf16 = 28800 fl
// ---- tier-1 extras (bf16 weight caches) ----
constexpr long OFF_GW    = OFF_XBF  + 28800;        // [4096][1792] bf16
constexpr long OFF_PW    = OFF_GW   + 3670016;      // [480][1024] bf16
constexpr long OFF_OW    = OFF_PW   + 245760;       // [16000][1280] bf16
constexpr long WS_NEED1  = OFF_OW   + 10240000;     // ~70.9 MB
// ---- tier-2 extras (bf16 state history + proj bias) ----
constexpr long OFF_HBF   = WS_NEED1;                // 65*32768 bf16 = 1,064,960 fl
constexpr long OFF_RVBF  = OFF_HBF  + 1064960;      // 65*8192 bf16 = 266,240 fl
constexpr long OFF_PB    = OFF_RVBF + 266240;       // 480 fl
constexpr long WS_NEED2  = OFF_PB   + 480;          // ~76.2 MB

__device__ __forceinline__ float sigm(float x) { return 1.f / (1.f + expf(-x)); }
__device__ __forceinline__ float oneplus_(float x) {
  return 1.f + fmaxf(x, 0.f) + log1pf(expf(-fabsf(x)));
}
__device__ __forceinline__ unsigned short f2bf(float f) {
  unsigned int u = __float_as_uint(f);
  unsigned int r = (u + 0x7FFFu + ((u >> 16) & 1u)) >> 16;
  return (unsigned short)r;
}

typedef __attribute__((ext_vector_type(8))) short bf16x8;
typedef __attribute__((ext_vector_type(4))) float f32x4;

// ===== src width auto-detect + decode to int32 =============================
__global__ void src_decode(const void* __restrict__ src_raw, float* __restrict__ ws) {
  __shared__ int is64_s;
  if (threadIdx.x == 0) is64_s = 1;
  __syncthreads();
  const long long* s64 = (const long long*)src_raw;
  for (int i = threadIdx.x; i < 1024; i += 256) {
    long long v = s64[i];
    if (v < 0 || v >= 32000) is64_s = 0;
  }
  __syncthreads();
  int* dst = (int*)(ws + OFF_SRC);
  if (is64_s) {
    for (int i = threadIdx.x; i < 2048; i += 256) dst[i] = (int)s64[i];
  } else {
    const int* s32 = (const int*)src_raw;
    for (int i = threadIdx.x; i < 2048; i += 256) dst[i] = s32[i];
  }
}

// ===== init ================================================================
__global__ void init_kernel(float* ws, const float* __restrict__ emb) {
  long i0 = (long)blockIdx.x * blockDim.x + threadIdx.x;
  long stride = (long)gridDim.x * blockDim.x;
  for (long x = i0; x < 32768; x += stride) ws[OFF_H + x] = 0.f;
  for (long x = i0; x < 8192;  x += stride) ws[OFF_RV + x] = 0.f;
  const long zlen = OFF_PROJ - OFF_S;
  for (long x = i0; x < zlen; x += stride) {
    long g = OFF_S + x;
    ws[g] = (g >= OFF_U && g < OFF_U + 4096) ? EPSF : 0.f;
  }
  unsigned short* Xg = (unsigned short*)(ws + OFF_XBF);
  const int* src = (const int*)(ws + OFF_SRC);
  for (long x = i0; x < 32 * 1800; x += stride) {
    int b = (int)(x / 1800), k = (int)(x % 1800);
    float v = (k < 512) ? emb[(long)src[b] * 512 + k] : 0.f;
    Xg[x] = f2bf(v);
  }
}

// ===== weight converters ===================================================
__global__ void wconv_gates(const float* __restrict__ W_ih, const float* __restrict__ W_hh,
                            float* __restrict__ ws) {
  unsigned short* GW = (unsigned short*)(ws + OFF_GW);
  long i0 = (long)blockIdx.x * blockDim.x + threadIdx.x;
  long stride = (long)gridDim.x * blockDim.x;
  const long ngroups = 4096L * 1792 / 4;
  for (long g = i0; g < ngroups; g += stride) {
    long row = g / 448, k = (g % 448) * 4;
    const float* src = (k < 768) ? (W_ih + row * 768 + k) : (W_hh + row * 1024 + (k - 768));
    float4 v = *(const float4*)src;
    unsigned short* d = &GW[row * 1792 + k];
    d[0] = f2bf(v.x); d[1] = f2bf(v.y); d[2] = f2bf(v.z); d[3] = f2bf(v.w);
  }
}

__global__ void wconv_proj(float* __restrict__ ws, int fill_pb,
    const float* rk_w, const float* rs_w, const float* fg_w, const float* rm_w,
    const float* wk_w, const float* ws_w, const float* ev_w, const float* wv_w,
    const float* ag_w, const float* wg_w,
    const float* rk_b, const float* rs_b, const float* fg_b, const float* rm_b,
    const float* wk_b, const float* ws_b, const float* ev_b, const float* wv_b,
    const float* ag_b, const float* wg_b) {
  unsigned short* PW = (unsigned short*)(ws + OFF_PW);
  long i0 = (long)blockIdx.x * blockDim.x + threadIdx.x;
  long stride = (long)gridDim.x * blockDim.x;
  const long ngroups = 471L * 256;
  for (long g = i0; g < ngroups; g += stride) {
    int o = (int)(g / 256), k = (int)(g % 256) * 4;
    const float* w;
    if (o < 256)      { int wi = o >> 2, hh = o & 3; w = rk_w + (long)(hh * 64 + wi) * 1024; }
    else if (o < 260) { w = rs_w + (long)(o - 256) * 1024; }
    else if (o < 264) { w = fg_w + (long)(o - 260) * 1024; }
    else if (o < 276) { int q2 = o - 264, m = q2 >> 2, hh = q2 & 3; w = rm_w + (long)(hh * 3 + m) * 1024; }
    else if (o < 340) { w = wk_w + (long)(o - 276) * 1024; }
    else if (o == 340){ w = ws_w; }
    else if (o < 405) { w = ev_w + (long)(o - 341) * 1024; }
    else if (o < 469) { w = wv_w + (long)(o - 405) * 1024; }
    else if (o == 469){ w = ag_w; }
    else              { w = wg_w; }
    float4 v = *(const float4*)(w + k);
    unsigned short* d = &PW[(long)o * 1024 + k];
    d[0] = f2bf(v.x); d[1] = f2bf(v.y); d[2] = f2bf(v.z); d[3] = f2bf(v.w);
  }
  if (fill_pb) {
    float* PB = ws + OFF_PB;
    for (long o = i0; o < 471; o += stride) {
      float bias;
      if (o < 256)      { int wi = (int)o >> 2, hh = (int)o & 3; bias = rk_b[hh * 64 + wi]; }
      else if (o < 260) { bias = rs_b[o - 256]; }
      else if (o < 264) { bias = fg_b[o - 260]; }
      else if (o < 276) { long q2 = o - 264, m = q2 >> 2, hh = q2 & 3; bias = rm_b[hh * 3 + m]; }
      else if (o < 340) { bias = wk_b[o - 276]; }
      else if (o == 340){ bias = ws_b[0]; }
      else if (o < 405) { bias = ev_b[o - 341]; }
      else if (o < 469) { bias = wv_b[o - 405]; }
      else if (o == 469){ bias = ag_b[0]; }
      else              { bias = wg_b[0]; }
      PB[o] = bias;
    }
  }
}

__global__ void wconv_out(const float* __restrict__ Why_w, const float* __restrict__ Wry_w,
                          float* __restrict__ ws) {
  unsigned short* OW = (unsigned short*)(ws + OFF_OW);
  long i0 = (long)blockIdx.x * blockDim.x + threadIdx.x;
  long stride = (long)gridDim.x * blockDim.x;
  const long ngroups = 16000L * 1280 / 4;
  for (long g = i0; g < ngroups; g += stride) {
    long row = g / 320, k = (g % 320) * 4;
    const float* src = (k < 1024) ? (Why_w + row * 1024 + k) : (Wry_w + row * 256 + (k - 1024));
    float4 v = *(const float4*)src;
    unsigned short* d = &OW[row * 1280 + k];
    d[0] = f2bf(v.x); d[1] = f2bf(v.y); d[2] = f2bf(v.z); d[3] = f2bf(v.w);
  }
}

// ===== gates_mfma v4: 256 blocks x 256 thr; 4 j/block; waves=K-quarters ====
// 16 cols = 4 gates x 4 j (g=rsel>>2, jl=rsel&3). gle [4][512] + Xs [32][1800]
constexpr int GSMF = 2048 + 28800;   // floats (123,392 B)
template <int BF, int HBW>
__global__ __launch_bounds__(256) void gates_mfma(
    int t, const float* __restrict__ W_ih, const float* __restrict__ W_hh,
    const float* __restrict__ b_ih, const float* __restrict__ b_hh,
    float* __restrict__ ws) {
  extern __shared__ float gsm[];
  float* gle = gsm;                                   // [4][512]
  unsigned short* Xs = (unsigned short*)(gsm + 2048); // [32][1800]
  int tid = threadIdx.x;
  int j0 = blockIdx.x * 4;
  {
    const uint4* Xg4 = (const uint4*)(ws + OFF_XBF);
    uint4* Xs4 = (uint4*)Xs;
    for (int i = tid; i < 7200; i += 256) Xs4[i] = Xg4[i];
  }
  __syncthreads();
  int wv = tid >> 6, lane = tid & 63;
  int kh = wv;                         // K-quarter
  int rsel = lane & 15;
  int kbase = (lane >> 4) * 8 + kh * 448;
  int g = rsel >> 2;
  int jl = rsel & 3;
  long nrow = (long)g * 1024 + j0 + jl;
  const unsigned short* GW = (const unsigned short*)(ws + OFF_GW);
  f32x4 acc0 = (f32x4){0.f, 0.f, 0.f, 0.f};
  f32x4 acc1 = (f32x4){0.f, 0.f, 0.f, 0.f};
  for (int kt = 0; kt < 14; ++kt) {
    int k = kbase + 32 * kt;
    bf16x8 bfr;
    if (BF) {
      bfr = *(const bf16x8*)&GW[nrow * 1792 + k];
    } else {
      const float* wsrc = (k < 768) ? (W_ih + nrow * 768 + k)
                                    : (W_hh + nrow * 1024 + (k - 768));
      float4 v0 = *(const float4*)(wsrc);
      float4 v1 = *(const float4*)(wsrc + 4);
      bfr[0] = (short)f2bf(v0.x); bfr[1] = (short)f2bf(v0.y);
      bfr[2] = (short)f2bf(v0.z); bfr[3] = (short)f2bf(v0.w);
      bfr[4] = (short)f2bf(v1.x); bfr[5] = (short)f2bf(v1.y);
      bfr[6] = (short)f2bf(v1.z); bfr[7] = (short)f2bf(v1.w);
    }
    bf16x8 a0 = *(const bf16x8*)&Xs[rsel * 1800 + k];
    bf16x8 a1 = *(const bf16x8*)&Xs[(16 + rsel) * 1800 + k];
    acc0 = __builtin_amdgcn_mfma_f32_16x16x32_bf16(a0, bfr, acc0, 0, 0, 0);
    acc1 = __builtin_amdgcn_mfma_f32_16x16x32_bf16(a1, bfr, acc1, 0, 0, 0);
  }
  // write per-wave partials (C: col=rsel, row=(lane>>4)*4+jj = batch)
#pragma unroll
  for (int jj = 0; jj < 4; ++jj) {
    int b0 = (lane >> 4) * 4 + jj;
    gle[wv * 512 + b0 * 16 + rsel] = acc0[jj];
    gle[wv * 512 + (b0 + 16) * 16 + rsel] = acc1[jj];
  }
  __syncthreads();
  if (tid < 128) {
    unsigned short* Xg = (unsigned short*)(ws + OFF_XBF);
    int b = tid >> 2, jle = tid & 3;
    int j = j0 + jle;
    float gi = gle[0 * 512 + b * 16 + jle]      + gle[1 * 512 + b * 16 + jle]
             + gle[2 * 512 + b * 16 + jle]      + gle[3 * 512 + b * 16 + jle]
             + b_ih[j] + b_hh[j];
    float gf = gle[0 * 512 + b * 16 + 4 + jle]  + gle[1 * 512 + b * 16 + 4 + jle]
             + gle[2 * 512 + b * 16 + 4 + jle]  + gle[3 * 512 + b * 16 + 4 + jle]
             + b_ih[1024 + j] + b_hh[1024 + j];
    float gg = gle[0 * 512 + b * 16 + 8 + jle]  + gle[1 * 512 + b * 16 + 8 + jle]
             + gle[2 * 512 + b * 16 + 8 + jle]  + gle[3 * 512 + b * 16 + 8 + jle]
             + b_ih[2048 + j] + b_hh[2048 + j];
    float go = gle[0 * 512 + b * 16 + 12 + jle] + gle[1 * 512 + b * 16 + 12 + jle]
             + gle[2 * 512 + b * 16 + 12 + jle] + gle[3 * 512 + b * 16 + 12 + jle]
             + b_ih[3072 + j] + b_hh[3072 + j];
    long si = (long)b * 1024 + j;
    float sv = sigm(gf) * ws[OFF_S + si] + sigm(gi) * tanhf(gg);
    ws[OFF_S + si] = sv;
    float hv = sigm(go) * tanhf(sv);
    ws[OFF_H + (long)(t + 1) * 32768 + si] = hv;
    unsigned short hb = f2bf(hv);
    Xg[(long)b * 1800 + 768 + j] = hb;
    if (HBW) {
      unsigned short* HB = (unsigned short*)(ws + OFF_HBF);
      HB[(long)(t + 1) * 32768 + si] = hb;
    }
  }
}

// ===== proj_mfma<BF> (r22 exact): used in tiers 0/1 only ===================
template <int BF>
__global__ __launch_bounds__(256) void proj_mfma(
    int t, float* __restrict__ ws,
    const float* rk_w, const float* rk_b, const float* rs_w, const float* rs_b,
    const float* fg_w, const float* fg_b, const float* rm_w, const float* rm_b,
    const float* wk_w, const float* wk_b, const float* ws_w, const float* ws_b,
    const float* ev_w, const float* ev_b, const float* wv_w, const float* wv_b,
    const float* ag_w, const float* ag_b, const float* wg_w, const float* wg_b) {
  __shared__ float pacc[4][512];
  __shared__ float pbias[16];
  int tid = threadIdx.x;
  int wv = tid >> 6, lane = tid & 63;
  int rsel = lane & 15, kofs = (lane >> 4) * 8;
  int o = blockIdx.x * 16 + rsel;
  const float* w;
  float bias;
  int ov = (o < 471) ? o : 470;
  if (ov < 256)      { int wi = ov >> 2, hh = ov & 3; w = rk_w + (long)(hh * 64 + wi) * 1024; bias = rk_b[hh * 64 + wi]; }
  else if (ov < 260) { int q2 = ov - 256; w = rs_w + (long)q2 * 1024; bias = rs_b[q2]; }
  else if (ov < 264) { int q2 = ov - 260; w = fg_w + (long)q2 * 1024; bias = fg_b[q2]; }
  else if (ov < 276) { int q2 = ov - 264, m = q2 >> 2, hh = q2 & 3; w = rm_w + (long)(hh * 3 + m) * 1024; bias = rm_b[hh * 3 + m]; }
  else if (ov < 340) { int q2 = ov - 276; w = wk_w + (long)q2 * 1024; bias = wk_b[q2]; }
  else if (ov == 340){ w = ws_w; bias = ws_b[0]; }
  else if (ov < 405) { int q2 = ov - 341; w = ev_w + (long)q2 * 1024; bias = ev_b[q2]; }
  else if (ov < 469) { int q2 = ov - 405; w = wv_w + (long)q2 * 1024; bias = wv_b[q2]; }
  else if (ov == 469){ w = ag_w; bias = ag_b[0]; }
  else               { w = wg_w; bias = wg_b[0]; }
  if (wv == 0 && lane < 16) pbias[rsel] = bias;
  const unsigned short* Xg = (const unsigned short*)(ws + OFF_XBF);
  const unsigned short* PW = (const unsigned short*)(ws + OFF_PW);
  f32x4 acc0 = (f32x4){0.f, 0.f, 0.f, 0.f};
  f32x4 acc1 = (f32x4){0.f, 0.f, 0.f, 0.f};
#pragma unroll
  for (int kt = 0; kt < 8; ++kt) {
    int k = wv * 256 + kofs + 32 * kt;   // 0..1023
    bf16x8 bfr;
    if (BF) {
      bfr = *(const bf16x8*)&PW[(long)ov * 1024 + k];
    } else {
      float4 v0 = *(const float4*)(w + k);
      float4 v1 = *(const float4*)(w + k + 4);
      bfr[0] = (short)f2bf(v0.x); bfr[1] = (short)f2bf(v0.y);
      bfr[2] = (short)f2bf(v0.z); bfr[3] = (short)f2bf(v0.w);
      bfr[4] = (short)f2bf(v1.x); bfr[5] = (short)f2bf(v1.y);
      bfr[6] = (short)f2bf(v1.z); bfr[7] = (short)f2bf(v1.w);
    }
    bf16x8 a0 = *(const bf16x8*)&Xg[(long)rsel * 1800 + 768 + k];
    bf16x8 a1 = *(const bf16x8*)&Xg[(long)(16 + rsel) * 1800 + 768 + k];
    acc0 = __builtin_amdgcn_mfma_f32_16x16x32_bf16(a0, bfr, acc0, 0, 0, 0);
    acc1 = __builtin_amdgcn_mfma_f32_16x16x32_bf16(a1, bfr, acc1, 0, 0, 0);
  }
#pragma unroll
  for (int jj = 0; jj < 4; ++jj) {
    int b0 = (lane >> 4) * 4 + jj;
    pacc[wv][b0 * 16 + rsel] = acc0[jj];
    pacc[wv][(b0 + 16) * 16 + rsel] = acc1[jj];
  }
  __syncthreads();
  for (int idx = tid; idx < 512; idx += 256) {
    int b = idx >> 4, ol = idx & 15;
    int o2 = blockIdx.x * 16 + ol;
    if (o2 < 471) {
      float s = pacc[0][idx] + pacc[1][idx] + pacc[2][idx] + pacc[3][idx];
      ws[OFF_PROJ + (long)b * 512 + o2] = s + pbias[ol];
    }
  }
}

// ===== shuffle reductions ==================================================
__device__ __forceinline__ float red128_max(float v, float* red, int tid) {
#pragma unroll
  for (int off = 32; off; off >>= 1) v = fmaxf(v, __shfl_xor(v, off));
  if (tid < 128 && (tid & 63) == 0) red[tid >> 6] = v;
  __syncthreads();
  float r = fmaxf(red[0], red[1]);
  __syncthreads();
  return r;
}
__device__ __forceinline__ float red128_sum(float v, float* red, int tid) {
#pragma unroll
  for (int off = 32; off; off >>= 1) v += __shfl_xor(v, off);
  if (tid < 128 && (tid & 63) == 0) red[tid >> 6] = v;
  __syncthreads();
  float r = red[0] + red[1];
  __syncthreads();
  return r;
}

// ===== memAB<FUSE,RBW>: optional fused proj prologue + rv bf16 history =====
constexpr int SMEMF  = 28744;           // base floats
constexpr int SMEMF2 = 28744 + 512 + 1024;  // + pjl + hsh (121,120 B)
template <int FUSE, int RBW>
__global__ __launch_bounds__(256) void memAB_kernel(
    int t, float* __restrict__ ws, const float* __restrict__ emb) {
  extern __shared__ float sm[];
  float* mem_s = sm;               // [128][65]  8320
  float* lk_s  = sm + 8320;        // [128][129] 16512
  float* red   = sm + 24832;       // 8
  float* wwl   = sm + 24840;       // 128
  float* pl    = sm + 24968;       // 128
  float* kwl   = sm + 25096;       // 64
  float* knl   = sm + 25160;       // 64
  float* dl    = sm + 25224;       // 64
  float* kl    = sm + 25288;       // 256
  float* rwold = sm + 25544;       // 512
  float* rwnew = sm + 26056;       // 512
  float* fpart = sm + 26568;       // 1024
  float* bpart = sm + 27592;       // 1024
  float* su    = sm + 28616;       // 128
  float* pjl   = sm + 28744;       // 512 (FUSE)
  float* hsh   = sm + 29256;       // 1024 (FUSE)
  int b = blockIdx.x, tid = threadIdx.x;
  int n = tid & 127, half = tid >> 7, lane = tid & 63;
  float* u    = ws + OFF_U  + b * 128;
  float* wwp  = ws + OFF_WW + b * 128;
  float* pp   = ws + OFF_P  + b * 128;
  float* rwp  = ws + OFF_RW + b * 512;
  float* memp = ws + OFF_MEM + (long)b * 8192;
  float* lk   = ws + OFF_LINKS + (long)b * 16384;

  // ---- fused proj prologue (tier-2): pjl[o] = h_bf16 . PW[o] + PB[o] ------
  if (FUSE) {
    const unsigned short* Xgb = (const unsigned short*)(ws + OFF_XBF) + (long)b * 1800 + 768;
    for (int i = tid; i < 1024; i += 256)
      hsh[i] = __uint_as_float(((unsigned int)Xgb[i]) << 16);
    __syncthreads();
    const unsigned short* PW = (const unsigned short*)(ws + OFF_PW);
    const float* PB = ws + OFF_PB;
    for (int o = tid; o < 471; o += 256) {
      const uint4* wr4 = (const uint4*)&PW[(long)o * 1024];
      float s = 0.f;
      for (int kq = 0; kq < 128; ++kq) {
        uint4 wv4 = wr4[kq];
        int k = kq * 8;
        s += __uint_as_float((wv4.x & 0xFFFFu) << 16) * hsh[k];
        s += __uint_as_float(wv4.x & 0xFFFF0000u)     * hsh[k + 1];
        s += __uint_as_float((wv4.y & 0xFFFFu) << 16) * hsh[k + 2];
        s += __uint_as_float(wv4.y & 0xFFFF0000u)     * hsh[k + 3];
        s += __uint_as_float((wv4.z & 0xFFFFu) << 16) * hsh[k + 4];
        s += __uint_as_float(wv4.z & 0xFFFF0000u)     * hsh[k + 5];
        s += __uint_as_float((wv4.w & 0xFFFFu) << 16) * hsh[k + 6];
        s += __uint_as_float(wv4.w & 0xFFFF0000u)     * hsh[k + 7];
      }
      pjl[o] = s + PB[o];
    }
    __syncthreads();
  }
  const float* pj = FUSE ? pjl : (ws + OFF_PROJ + b * 512);

  for (int i = tid; i < 8192; i += 256) mem_s[(i >> 6) * 65 + (i & 63)] = memp[i];
  for (int i = tid; i < 16384; i += 256) lk_s[(i >> 7) * 129 + (i & 127)] = lk[i];

  float uu = 0.f;
  if (half == 0) {
    float fg0 = sigm(pj[260]), fg1 = sigm(pj[261]), fg2 = sigm(pj[262]), fg3 = sigm(pj[263]);
    float r0 = rwp[n * 4], r1 = rwp[n * 4 + 1], r2 = rwp[n * 4 + 2], r3 = rwp[n * 4 + 3];
    rwold[n * 4] = r0; rwold[n * 4 + 1] = r1; rwold[n * 4 + 2] = r2; rwold[n * 4 + 3] = r3;
    float psi = expf(logf(1.f - fg0 * r0) + logf(1.f - fg1 * r1) +
                     logf(1.f - fg2 * r2) + logf(1.f - fg3 * r3));
    float u0 = u[n], wwo = wwp[n];
    uu = (u0 + wwo - u0 * wwo) * psi;
    u[n] = uu;
  }
  if (tid < 64) {
    kwl[tid] = pj[276 + tid];
    dl[tid] = sigm(pj[405 + tid]) - sigm(pj[341 + tid]);  // writev - erase
  }
  if (tid >= 128 && tid < 192) {
    int q = tid - 128;
#pragma unroll
    for (int h = 0; h < 4; ++h) kl[q * 4 + h] = pj[q * 4 + h];
  }
  __syncthreads();
  float kn2 = 0.f;
#pragma unroll
  for (int w = 0; w < 64; ++w) kn2 += kwl[w] * kwl[w];
  float kn = sqrtf(kn2);
  if (tid < 64) knl[tid] = kwl[tid] / kn;

  float v = uu;
  if (half == 0) {
#pragma unroll
    for (int k = 2; k <= 64; k <<= 1) {
#pragma unroll
      for (int j = k >> 1; j > 0; j >>= 1) {
        float other = __shfl_xor(v, j);
        bool up = ((n & k) == 0);
        bool high = (n & j) != 0;
        float mn = fminf(v, other), mx2 = fmaxf(v, other);
        v = (high == up) ? mx2 : mn;
      }
    }
    su[n] = v;
  }
  __syncthreads();
  if (half == 0) {
    float other = su[n ^ 64];
    v = ((n & 64) != 0) ? fmaxf(v, other) : fminf(v, other);
#pragma unroll
    for (int j = 32; j > 0; j >>= 1) {
      float other2 = __shfl_xor(v, j);
      bool high = (n & j) != 0;
      v = high ? fmaxf(v, other2) : fminf(v, other2);
    }
  }
  float lgv = 0.f;
  if (half == 0) {
    lgv = logf(v);
#pragma unroll
    for (int d = 1; d < 64; d <<= 1) {
      float t2 = __shfl_up(lgv, d);
      lgv = (lane >= d) ? lgv + t2 : lgv;
    }
  }
  if (tid == 63) red[0] = lgv;
  __syncthreads();
  if (half == 0 && (tid >> 6) == 1) lgv += red[0];
  __syncthreads();
  float mrow[64];
  float score = -3.4e38f, e = 0.f, wwn = 0.f, a_n = 0.f;
  if (half == 0) {
    a_n = (1.f - v) * expf(lgv - logf(v));
    float sq = 0.f;
#pragma unroll
    for (int w = 0; w < 64; ++w) { float m = mem_s[n * 65 + w]; mrow[w] = m; sq += m * m; }
    float den = sqrtf(sq) + EPSF;
#pragma unroll
    for (int w = 0; w < 64; ++w) mrow[w] = mrow[w] / den;
    float dot = 0.f;
#pragma unroll
    for (int w = 0; w < 64; ++w) dot += mrow[w] * knl[w];
    score = dot * oneplus_(pj[340]);
  }
  float mx = red128_max(score, red, tid);
  e = (half == 0) ? expf(score - mx) : 0.f;
  float esum = red128_sum(e, red, tid);
  if (half == 0) {
    float cw = e / esum;
    float ag = sigm(pj[469]), wg = sigm(pj[470]);
    wwn = wg * (ag * a_n + (1.f - ag) * cw);
    wwp[n] = wwn; wwl[n] = wwn;
  }
  float sumww = red128_sum((half == 0) ? wwn : 0.f, red, tid);
  if (half == 0) {
    float pn = (1.f - sumww) * pp[n] + wwn;
    pp[n] = pn; pl[n] = pn;
  }
  __syncthreads();
  if (half == 0) {
#pragma unroll
    for (int w = 0; w < 64; ++w) mem_s[n * 65 + w] = mrow[w] + wwn * dl[w];
  }
  {
    float wn = wwl[n], pcol = pl[n];
    int base = half * 64;
    for (int q = 0; q < 64; ++q) {
      int k2 = base + q;
      float lv = lk_s[k2 * 129 + n] * (1.f - (wwl[k2] + wn)) + wwl[k2] * pcol;
      lk_s[k2 * 129 + n] = (k2 == n) ? 0.f : lv;
    }
  }
  __syncthreads();

  if (half == 0) {
    float sq = 0.f;
#pragma unroll
    for (int w = 0; w < 64; ++w) { float m = mem_s[n * 65 + w]; mrow[w] = m; sq += m * m; }
    float den2 = sqrtf(sq) + EPSF;
#pragma unroll
    for (int w = 0; w < 64; ++w) { mrow[w] = mrow[w] / den2; mem_s[n * 65 + w] = mrow[w]; }
  }
  __syncthreads();
  float cr_[4];
#pragma unroll
  for (int h = 0; h < 4; ++h) {
    float s3 = 0.f;
#pragma unroll
    for (int w = 0; w < 64; ++w) { float kv = kl[w * 4 + h]; s3 += kv * kv; }
    float knh = sqrtf(s3);
    float sc = -3.4e38f;
    if (half == 0) {
      float d2 = 0.f;
#pragma unroll
      for (int w = 0; w < 64; ++w) d2 += mrow[w] * (kl[w * 4 + h] / knh);
      sc = d2 * oneplus_(pj[256 + h]);
    }
    float mxh = red128_max(sc, red, tid);
    float eh = (half == 0) ? expf(sc - mxh) : 0.f;
    float ehs = red128_sum(eh, red, tid);
    cr_[h] = eh / ehs;
  }
  {
    float f0 = 0, f1 = 0, f2 = 0, f3 = 0, b0 = 0, b1 = 0, b2 = 0, b3 = 0;
    int base = half * 64;
    for (int q = 0; q < 64; ++q) {
      int jj = base + q;
      float lrow = lk_s[n * 129 + jj];
      float lcol = lk_s[jj * 129 + n];
      float q0 = rwold[jj * 4], q1 = rwold[jj * 4 + 1], q2 = rwold[jj * 4 + 2], q3 = rwold[jj * 4 + 3];
      f0 += lrow * q0; f1 += lrow * q1; f2 += lrow * q2; f3 += lrow * q3;
      b0 += lcol * q0; b1 += lcol * q1; b2 += lcol * q2; b3 += lcol * q3;
    }
    int o = half * 512 + n * 4;
    fpart[o] = f0; fpart[o + 1] = f1; fpart[o + 2] = f2; fpart[o + 3] = f3;
    bpart[o] = b0; bpart[o + 1] = b1; bpart[o + 2] = b2; bpart[o + 3] = b3;
  }
  __syncthreads();
  if (half == 0) {
#pragma unroll
    for (int h = 0; h < 4; ++h) {
      float fv = fpart[n * 4 + h] + fpart[512 + n * 4 + h];
      float bv = bpart[n * 4 + h] + bpart[512 + n * 4 + h];
      float m0 = pj[264 + h], m1 = pj[264 + 4 + h], m2 = pj[264 + 8 + h];
      float mm = fmaxf(m0, fmaxf(m1, m2));
      float e0 = expf(m0 - mm), e1 = expf(m1 - mm), e2 = expf(m2 - mm);
      float inv = 1.f / (e0 + e1 + e2);
      float rwv = (e0 * inv) * bv + (e1 * inv) * cr_[h] + (e2 * inv) * fv;
      rwp[n * 4 + h] = rwv;
      rwnew[n * 4 + h] = rwv;
    }
  }
  __syncthreads();
  for (int i = tid; i < 8192; i += 256) memp[i] = mem_s[(i >> 6) * 65 + (i & 63)];
  for (int i = tid; i < 16384; i += 256) lk[i] = lk_s[(i >> 7) * 129 + (i & 127)];
  unsigned short* Xg = (unsigned short*)(ws + OFF_XBF);
  {
    int w2 = tid & 63, which = tid >> 6;
    float rv = 0.f;
    for (int jj = 0; jj < 128; ++jj) rv += mem_s[jj * 65 + w2] * rwnew[jj * 4 + which];
    ws[OFF_RV + (long)(t + 1) * 8192 + b * 256 + w2 * 4 + which] = rv;
    unsigned short rb = f2bf(rv);
    Xg[(long)b * 1800 + 512 + w2 * 4 + which] = rb;
    if (RBW) {
      unsigned short* RB = (unsigned short*)(ws + OFF_RVBF);
      RB[(long)(t + 1) * 8192 + b * 256 + w2 * 4 + which] = rb;
    }
  }
  if (t + 1 < TN) {
    int nsrc = ((const int*)(ws + OFF_SRC))[(t + 1) * 32 + b];
    const float* eb = emb + (long)nsrc * 512;
    for (int i = tid; i < 512; i += 256) Xg[(long)b * 1800 + i] = f2bf(eb[i]);
  }
}

// ===== out_gemm_mfma<BF,ABF> ===============================================
template <int BF, int ABF>
__global__ __launch_bounds__(512) void out_gemm_mfma(
    const float* __restrict__ ws, const float* __restrict__ Why_w,
    const float* __restrict__ Why_b, const float* __restrict__ Wry_w,
    float* __restrict__ out) {
  __shared__ unsigned short As[256 * 40];
  __shared__ unsigned short Bs[128 * 40];
  const float* Hp  = ws + OFF_H + 32768;   // [2048][1024]
  const float* RVp = ws + OFF_RV + 8192;   // [2048][256]
  const unsigned short* OW = (const unsigned short*)(ws + OFF_OW);
  const unsigned short* HB16 = (const unsigned short*)(ws + OFF_HBF) + 32768;
  const unsigned short* RB16 = (const unsigned short*)(ws + OFF_RVBF) + 8192;
  int tid = threadIdx.x;
  int wv = tid >> 6, lane = tid & 63;
  int wr = wv >> 1, wc = wv & 1;
  int col0 = blockIdx.x * 128, row0 = blockIdx.y * 256;
  f32x4 acc[4][4];
#pragma unroll
  for (int i = 0; i < 4; ++i)
#pragma unroll
    for (int j = 0; j < 4; ++j) acc[i][j] = (f32x4){0.f, 0.f, 0.f, 0.f};

  for (int kt = 0; kt < 40; ++kt) {
    int k0 = kt * 32;
    __syncthreads();
    {
      int r = tid >> 1, kh = tid & 1;
      int gk = k0 + kh * 16;
      long grow = row0 + r;
      if (ABF) {
        const unsigned short* srcb = (gk < 1024) ? (HB16 + grow * 1024 + gk)
                                                 : (RB16 + grow * 256 + (gk - 1024));
        uint4 p0 = *(const uint4*)(srcb);
        uint4 p1 = *(const uint4*)(srcb + 8);
        unsigned short* d = &As[r * 40 + kh * 16];
        *(uint4*)d = p0;
        *(uint4*)(d + 8) = p1;
      } else {
        const float* src = (gk < 1024) ? (Hp + grow * 1024 + gk)
                                       : (RVp + grow * 256 + (gk - 1024));
        float4 v0 = *(const float4*)(src);
        float4 v1 = *(const float4*)(src + 4);
        float4 v2 = *(const float4*)(src + 8);
        float4 v3 = *(const float4*)(src + 12);
        unsigned short* d = &As[r * 40 + kh * 16];
        d[0] = f2bf(v0.x);  d[1] = f2bf(v0.y);  d[2] = f2bf(v0.z);  d[3] = f2bf(v0.w);
        d[4] = f2bf(v1.x);  d[5] = f2bf(v1.y);  d[6] = f2bf(v1.z);  d[7] = f2bf(v1.w);
        d[8] = f2bf(v2.x);  d[9] = f2bf(v2.y);  d[10] = f2bf(v2.z); d[11] = f2bf(v2.w);
        d[12] = f2bf(v3.x); d[13] = f2bf(v3.y); d[14] = f2bf(v3.z); d[15] = f2bf(v3.w);
      }
    }
    {
      int r = tid >> 2, ks = (tid & 3) * 8;
      int gk = k0 + ks;
      long wrow = col0 + r;
      if (BF) {
        *(uint4*)&Bs[r * 40 + ks] = *(const uint4*)&OW[wrow * 1280 + gk];
      } else {
        const float* src = (gk < 1024) ? (Why_w + wrow * 1024 + gk)
                                       : (Wry_w + wrow * 256 + (gk - 1024));
        float4 v0 = *(const float4*)(src);
        float4 v1 = *(const float4*)(src + 4);
        unsigned short* d = &Bs[r * 40 + ks];
        d[0] = f2bf(v0.x); d[1] = f2bf(v0.y); d[2] = f2bf(v0.z); d[3] = f2bf(v0.w);
        d[4] = f2bf(v1.x); d[5] = f2bf(v1.y); d[6] = f2bf(v1.z); d[7] = f2bf(v1.w);
      }
    }
    __syncthreads();
    bf16x8 afr[4], bfr[4];
    int kofs = (lane >> 4) * 8;
    int rsel = lane & 15;
#pragma unroll
    for (int mt = 0; mt < 4; ++mt)
      afr[mt] = *(const bf16x8*)&As[(wr * 64 + mt * 16 + rsel) * 40 + kofs];
#pragma unroll
    for (int nt = 0; nt < 4; ++nt)
      bfr[nt] = *(const bf16x8*)&Bs[(wc * 64 + nt * 16 + rsel) * 40 + kofs];
#pragma unroll
    for (int mt = 0; mt < 4; ++mt)
#pragma unroll
      for (int nt = 0; nt < 4; ++nt)
        acc[mt][nt] = __builtin_amdgcn_mfma_f32_16x16x32_bf16(afr[mt], bfr[nt], acc[mt][nt], 0, 0, 0);
  }
  int crow = (lane >> 4) * 4, ccol = lane & 15;
#pragma unroll
  for (int nt = 0; nt < 4; ++nt) {
    int gcol = col0 + wc * 64 + nt * 16 + ccol;
    float bias = Why_b[gcol];
#pragma unroll
    for (int mt = 0; mt < 4; ++mt) {
      long grow = row0 + wr * 64 + mt * 16 + crow;
#pragma unroll
      for (int j = 0; j < 4; ++j) {
        out[(grow + j) * 16000 + gcol] = acc[mt][nt][j] + bias;
      }
    }
  }
}

extern "C" void kernel_launch(void* const* d_in, const int* in_sizes, int n_in,
                              void* d_out, int out_size, void* d_ws, size_t ws_size,
                              hipStream_t stream) {
  const void* src_raw = d_in[0];
  const float* emb   = (const float*)d_in[1];
  const float* W_ih  = (const float*)d_in[2];
  const float* W_hh  = (const float*)d_in[3];
  const float* b_ih  = (const float*)d_in[4];
  const float* b_hh  = (const float*)d_in[5];
  const float* rk_w  = (const float*)d_in[6];
  const float* rk_b  = (const float*)d_in[7];
  const float* rs_w  = (const float*)d_in[8];
  const float* rs_b  = (const float*)d_in[9];
  const float* fg_w  = (const float*)d_in[10];
  const float* fg_b  = (const float*)d_in[11];
  const float* rm_w  = (const float*)d_in[12];
  const float* rm_b  = (const float*)d_in[13];
  const float* wk_w  = (const float*)d_in[14];
  const float* wk_b  = (const float*)d_in[15];
  const float* ws_w  = (const float*)d_in[16];
  const float* ws_b  = (const float*)d_in[17];
  const float* ev_w  = (const float*)d_in[18];
  const float* ev_b  = (const float*)d_in[19];
  const float* wv_w  = (const float*)d_in[20];
  const float* wv_b  = (const float*)d_in[21];
  const float* ag_w  = (const float*)d_in[22];
  const float* ag_b  = (const float*)d_in[23];
  const float* wg_w  = (const float*)d_in[24];
  const float* wg_b  = (const float*)d_in[25];
  const float* Why_w = (const float*)d_in[26];
  const float* Why_b = (const float*)d_in[27];
  const float* Wry_w = (const float*)d_in[28];
  float* ws = (float*)d_ws;
  float* out = (float*)d_out;

  const bool t2 = (ws_size >= (size_t)WS_NEED2 * sizeof(float));
  const bool t1 = !t2 && (ws_size >= (size_t)WS_NEED1 * sizeof(float));
  src_decode<<<1, 256, 0, stream>>>(src_raw, ws);
  init_kernel<<<512, 256, 0, stream>>>(ws, emb);
  if (t1 || t2) {
    wconv_gates<<<1024, 256, 0, stream>>>(W_ih, W_hh, ws);
    wconv_proj<<<471, 256, 0, stream>>>(ws, t2 ? 1 : 0,
                                        rk_w, rs_w, fg_w, rm_w, wk_w, ws_w,
                                        ev_w, wv_w, ag_w, wg_w,
                                        rk_b, rs_b, fg_b, rm_b, wk_b, ws_b,
                                        ev_b, wv_b, ag_b, wg_b);
    wconv_out<<<2048, 256, 0, stream>>>(Why_w, Wry_w, ws);
  }
  const size_t gsm_bytes = (size_t)GSMF * sizeof(float);
  for (int t = 0; t < TN; ++t) {
    if (t2)      gates_mfma<1, 1><<<256, 256, gsm_bytes, stream>>>(t, W_ih, W_hh, b_ih, b_hh, ws);
    else if (t1) gates_mfma<1, 0><<<256, 256, gsm_bytes, stream>>>(t, W_ih, W_hh, b_ih, b_hh, ws);
    else         gates_mfma<0, 0><<<256, 256, gsm_bytes, stream>>>(t, W_ih, W_hh, b_ih, b_hh, ws);
    if (!t2) {
      if (t1) proj_mfma<1><<<30, 256, 0, stream>>>(t, ws, rk_w, rk_b, rs_w, rs_b, fg_w, fg_b,
                                                   rm_w, rm_b, wk_w, wk_b, ws_w, ws_b,
                                                   ev_w, ev_b, wv_w, wv_b, ag_w, ag_b, wg_w, wg_b);
      else    proj_mfma<0><<<30, 256, 0, stream>>>(t, ws, rk_w, rk_b, rs_w, rs_b, fg_w, fg_b,
                                                   rm_w, rm_b, wk_w, wk_b, ws_w, ws_b,
                                                   ev_w, ev_b, wv_w, wv_b, ag_w, ag_b, wg_w, wg_b);
    }
    if (t2) memAB_kernel<1, 1><<<32, 256, (size_t)SMEMF2 * sizeof(float), stream>>>(t, ws, emb);
    else    memAB_kernel<0, 0><<<32, 256, (size_t)SMEMF * sizeof(float), stream>>>(t, ws, emb);
  }
  if (t2)      out_gemm_mfma<1, 1><<<dim3(125, 8), 512, 0, stream>>>(ws, Why_w, Why_b, Wry_w, out);
  else if (t1) out_gemm_mfma<1, 0><<<dim3(125, 8), 512, 0, stream>>>(ws, Why_w, Why_b, Wry_w, out);
  else         out_gemm_mfma<0, 0><<<dim3(125, 8), 512, 0, stream>>>(ws, Why_w, Why_b, Wry_w, out);
}

// Round 24
// 3576.854 us; speedup vs baseline: 1.5475x; 1.5475x over previous
//
#include <hip/hip_runtime.h>
#include <math.h>

// ---- problem dims ----
#define TN 64
#define BN 32
#define EPSF 1e-6f

// ---- workspace layout (floats) ----
constexpr long OFF_H     = 0;                       // 65 * 32*1024
constexpr long OFF_RV    = OFF_H    + 65L*32768;    // 65 * 32*256
constexpr long OFF_S     = OFF_RV   + 65L*8192;     // 32768
constexpr long OFF_RW    = OFF_S    + 32768;        // B*N*HD = 16384
constexpr long OFF_WW    = OFF_RW   + 16384;        // B*N
constexpr long OFF_U     = OFF_WW   + 4096;
constexpr long OFF_P     = OFF_U    + 4096;
constexpr long OFF_MEM   = OFF_P    + 4096;         // B*N*WD = 262144
constexpr long OFF_LINKS = OFF_MEM  + 262144;       // B*N*N = 524288
constexpr long OFF_PROJ  = OFF_LINKS+ 524288;       // B*512 (471 used)
constexpr long OFF_SRC   = OFF_PROJ + 16384;        // 2048 ints
constexpr long OFF_XBF   = OFF_SRC  + 2048;         // 32*1800 bf16 = 28800 fl
// ---- tier-1 extras (bf16 weight caches) ----
constexpr long OFF_GW    = OFF_XBF  + 28800;        // [4096][1792] bf16
constexpr long OFF_PW    = OFF_GW   + 3670016;      // [480][1024] bf16
constexpr long OFF_OW    = OFF_PW   + 245760;       // [16000][1280] bf16
constexpr long WS_NEED1  = OFF_OW   + 10240000;     // ~70.9 MB
// ---- tier-2 extras (bf16 state history) ----
constexpr long OFF_HBF   = WS_NEED1;                // 65*32768 bf16 = 1,064,960 fl
constexpr long OFF_RVBF  = OFF_HBF  + 1064960;      // 65*8192 bf16 = 266,240 fl
constexpr long WS_NEED2  = OFF_RVBF + 266240;       // ~76.2 MB

__device__ __forceinline__ float sigm(float x) { return 1.f / (1.f + expf(-x)); }
__device__ __forceinline__ float oneplus_(float x) {
  return 1.f + fmaxf(x, 0.f) + log1pf(expf(-fabsf(x)));
}
__device__ __forceinline__ unsigned short f2bf(float f) {
  unsigned int u = __float_as_uint(f);
  unsigned int r = (u + 0x7FFFu + ((u >> 16) & 1u)) >> 16;
  return (unsigned short)r;
}

typedef __attribute__((ext_vector_type(8))) short bf16x8;
typedef __attribute__((ext_vector_type(4))) float f32x4;

// ===== src width auto-detect + decode to int32 =============================
__global__ void src_decode(const void* __restrict__ src_raw, float* __restrict__ ws) {
  __shared__ int is64_s;
  if (threadIdx.x == 0) is64_s = 1;
  __syncthreads();
  const long long* s64 = (const long long*)src_raw;
  for (int i = threadIdx.x; i < 1024; i += 256) {
    long long v = s64[i];
    if (v < 0 || v >= 32000) is64_s = 0;
  }
  __syncthreads();
  int* dst = (int*)(ws + OFF_SRC);
  if (is64_s) {
    for (int i = threadIdx.x; i < 2048; i += 256) dst[i] = (int)s64[i];
  } else {
    const int* s32 = (const int*)src_raw;
    for (int i = threadIdx.x; i < 2048; i += 256) dst[i] = s32[i];
  }
}

// ===== init ================================================================
__global__ void init_kernel(float* ws, const float* __restrict__ emb) {
  long i0 = (long)blockIdx.x * blockDim.x + threadIdx.x;
  long stride = (long)gridDim.x * blockDim.x;
  for (long x = i0; x < 32768; x += stride) ws[OFF_H + x] = 0.f;
  for (long x = i0; x < 8192;  x += stride) ws[OFF_RV + x] = 0.f;
  const long zlen = OFF_PROJ - OFF_S;
  for (long x = i0; x < zlen; x += stride) {
    long g = OFF_S + x;
    ws[g] = (g >= OFF_U && g < OFF_U + 4096) ? EPSF : 0.f;
  }
  unsigned short* Xg = (unsigned short*)(ws + OFF_XBF);
  const int* src = (const int*)(ws + OFF_SRC);
  for (long x = i0; x < 32 * 1800; x += stride) {
    int b = (int)(x / 1800), k = (int)(x % 1800);
    float v = (k < 512) ? emb[(long)src[b] * 512 + k] : 0.f;
    Xg[x] = f2bf(v);
  }
}

// ===== weight converters ===================================================
__global__ void wconv_gates(const float* __restrict__ W_ih, const float* __restrict__ W_hh,
                            float* __restrict__ ws) {
  unsigned short* GW = (unsigned short*)(ws + OFF_GW);
  long i0 = (long)blockIdx.x * blockDim.x + threadIdx.x;
  long stride = (long)gridDim.x * blockDim.x;
  const long ngroups = 4096L * 1792 / 4;
  for (long g = i0; g < ngroups; g += stride) {
    long row = g / 448, k = (g % 448) * 4;
    const float* src = (k < 768) ? (W_ih + row * 768 + k) : (W_hh + row * 1024 + (k - 768));
    float4 v = *(const float4*)src;
    unsigned short* d = &GW[row * 1792 + k];
    d[0] = f2bf(v.x); d[1] = f2bf(v.y); d[2] = f2bf(v.z); d[3] = f2bf(v.w);
  }
}

__global__ void wconv_proj(float* __restrict__ ws,
    const float* rk_w, const float* rs_w, const float* fg_w, const float* rm_w,
    const float* wk_w, const float* ws_w, const float* ev_w, const float* wv_w,
    const float* ag_w, const float* wg_w) {
  unsigned short* PW = (unsigned short*)(ws + OFF_PW);
  long i0 = (long)blockIdx.x * blockDim.x + threadIdx.x;
  long stride = (long)gridDim.x * blockDim.x;
  const long ngroups = 471L * 256;
  for (long g = i0; g < ngroups; g += stride) {
    int o = (int)(g / 256), k = (int)(g % 256) * 4;
    const float* w;
    if (o < 256)      { int wi = o >> 2, hh = o & 3; w = rk_w + (long)(hh * 64 + wi) * 1024; }
    else if (o < 260) { w = rs_w + (long)(o - 256) * 1024; }
    else if (o < 264) { w = fg_w + (long)(o - 260) * 1024; }
    else if (o < 276) { int q2 = o - 264, m = q2 >> 2, hh = q2 & 3; w = rm_w + (long)(hh * 3 + m) * 1024; }
    else if (o < 340) { w = wk_w + (long)(o - 276) * 1024; }
    else if (o == 340){ w = ws_w; }
    else if (o < 405) { w = ev_w + (long)(o - 341) * 1024; }
    else if (o < 469) { w = wv_w + (long)(o - 405) * 1024; }
    else if (o == 469){ w = ag_w; }
    else              { w = wg_w; }
    float4 v = *(const float4*)(w + k);
    unsigned short* d = &PW[(long)o * 1024 + k];
    d[0] = f2bf(v.x); d[1] = f2bf(v.y); d[2] = f2bf(v.z); d[3] = f2bf(v.w);
  }
}

__global__ void wconv_out(const float* __restrict__ Why_w, const float* __restrict__ Wry_w,
                          float* __restrict__ ws) {
  unsigned short* OW = (unsigned short*)(ws + OFF_OW);
  long i0 = (long)blockIdx.x * blockDim.x + threadIdx.x;
  long stride = (long)gridDim.x * blockDim.x;
  const long ngroups = 16000L * 1280 / 4;
  for (long g = i0; g < ngroups; g += stride) {
    long row = g / 320, k = (g % 320) * 4;
    const float* src = (k < 1024) ? (Why_w + row * 1024 + k) : (Wry_w + row * 256 + (k - 1024));
    float4 v = *(const float4*)src;
    unsigned short* d = &OW[row * 1280 + k];
    d[0] = f2bf(v.x); d[1] = f2bf(v.y); d[2] = f2bf(v.z); d[3] = f2bf(v.w);
  }
}

// ===== gates_mfma: 256 blocks x 256 thr; 4 j/block; waves=K-quarters =======
constexpr int GSMF = 2048 + 28800;   // floats (123,392 B)
template <int BF, int HBW>
__global__ __launch_bounds__(256) void gates_mfma(
    int t, const float* __restrict__ W_ih, const float* __restrict__ W_hh,
    const float* __restrict__ b_ih, const float* __restrict__ b_hh,
    float* __restrict__ ws) {
  extern __shared__ float gsm[];
  float* gle = gsm;                                   // [4][512]
  unsigned short* Xs = (unsigned short*)(gsm + 2048); // [32][1800]
  int tid = threadIdx.x;
  int j0 = blockIdx.x * 4;
  {
    const uint4* Xg4 = (const uint4*)(ws + OFF_XBF);
    uint4* Xs4 = (uint4*)Xs;
    for (int i = tid; i < 7200; i += 256) Xs4[i] = Xg4[i];
  }
  __syncthreads();
  int wv = tid >> 6, lane = tid & 63;
  int kh = wv;
  int rsel = lane & 15;
  int kbase = (lane >> 4) * 8 + kh * 448;
  int g = rsel >> 2;
  int jl = rsel & 3;
  long nrow = (long)g * 1024 + j0 + jl;
  const unsigned short* GW = (const unsigned short*)(ws + OFF_GW);
  f32x4 acc0 = (f32x4){0.f, 0.f, 0.f, 0.f};
  f32x4 acc1 = (f32x4){0.f, 0.f, 0.f, 0.f};
  for (int kt = 0; kt < 14; ++kt) {
    int k = kbase + 32 * kt;
    bf16x8 bfr;
    if (BF) {
      bfr = *(const bf16x8*)&GW[nrow * 1792 + k];
    } else {
      const float* wsrc = (k < 768) ? (W_ih + nrow * 768 + k)
                                    : (W_hh + nrow * 1024 + (k - 768));
      float4 v0 = *(const float4*)(wsrc);
      float4 v1 = *(const float4*)(wsrc + 4);
      bfr[0] = (short)f2bf(v0.x); bfr[1] = (short)f2bf(v0.y);
      bfr[2] = (short)f2bf(v0.z); bfr[3] = (short)f2bf(v0.w);
      bfr[4] = (short)f2bf(v1.x); bfr[5] = (short)f2bf(v1.y);
      bfr[6] = (short)f2bf(v1.z); bfr[7] = (short)f2bf(v1.w);
    }
    bf16x8 a0 = *(const bf16x8*)&Xs[rsel * 1800 + k];
    bf16x8 a1 = *(const bf16x8*)&Xs[(16 + rsel) * 1800 + k];
    acc0 = __builtin_amdgcn_mfma_f32_16x16x32_bf16(a0, bfr, acc0, 0, 0, 0);
    acc1 = __builtin_amdgcn_mfma_f32_16x16x32_bf16(a1, bfr, acc1, 0, 0, 0);
  }
#pragma unroll
  for (int jj = 0; jj < 4; ++jj) {
    int b0 = (lane >> 4) * 4 + jj;
    gle[wv * 512 + b0 * 16 + rsel] = acc0[jj];
    gle[wv * 512 + (b0 + 16) * 16 + rsel] = acc1[jj];
  }
  __syncthreads();
  if (tid < 128) {
    unsigned short* Xg = (unsigned short*)(ws + OFF_XBF);
    int b = tid >> 2, jle = tid & 3;
    int j = j0 + jle;
    float gi = gle[0 * 512 + b * 16 + jle]      + gle[1 * 512 + b * 16 + jle]
             + gle[2 * 512 + b * 16 + jle]      + gle[3 * 512 + b * 16 + jle]
             + b_ih[j] + b_hh[j];
    float gf = gle[0 * 512 + b * 16 + 4 + jle]  + gle[1 * 512 + b * 16 + 4 + jle]
             + gle[2 * 512 + b * 16 + 4 + jle]  + gle[3 * 512 + b * 16 + 4 + jle]
             + b_ih[1024 + j] + b_hh[1024 + j];
    float gg = gle[0 * 512 + b * 16 + 8 + jle]  + gle[1 * 512 + b * 16 + 8 + jle]
             + gle[2 * 512 + b * 16 + 8 + jle]  + gle[3 * 512 + b * 16 + 8 + jle]
             + b_ih[2048 + j] + b_hh[2048 + j];
    float go = gle[0 * 512 + b * 16 + 12 + jle] + gle[1 * 512 + b * 16 + 12 + jle]
             + gle[2 * 512 + b * 16 + 12 + jle] + gle[3 * 512 + b * 16 + 12 + jle]
             + b_ih[3072 + j] + b_hh[3072 + j];
    long si = (long)b * 1024 + j;
    float sv = sigm(gf) * ws[OFF_S + si] + sigm(gi) * tanhf(gg);
    ws[OFF_S + si] = sv;
    float hv = sigm(go) * tanhf(sv);
    ws[OFF_H + (long)(t + 1) * 32768 + si] = hv;
    unsigned short hb = f2bf(hv);
    Xg[(long)b * 1800 + 768 + j] = hb;
    if (HBW) {
      unsigned short* HB = (unsigned short*)(ws + OFF_HBF);
      HB[(long)(t + 1) * 32768 + si] = hb;
    }
  }
}

// ===== proj_mfma<BF> (r22 exact) ===========================================
template <int BF>
__global__ __launch_bounds__(256) void proj_mfma(
    int t, float* __restrict__ ws,
    const float* rk_w, const float* rk_b, const float* rs_w, const float* rs_b,
    const float* fg_w, const float* fg_b, const float* rm_w, const float* rm_b,
    const float* wk_w, const float* wk_b, const float* ws_w, const float* ws_b,
    const float* ev_w, const float* ev_b, const float* wv_w, const float* wv_b,
    const float* ag_w, const float* ag_b, const float* wg_w, const float* wg_b) {
  __shared__ float pacc[4][512];
  __shared__ float pbias[16];
  int tid = threadIdx.x;
  int wv = tid >> 6, lane = tid & 63;
  int rsel = lane & 15, kofs = (lane >> 4) * 8;
  int o = blockIdx.x * 16 + rsel;
  const float* w;
  float bias;
  int ov = (o < 471) ? o : 470;
  if (ov < 256)      { int wi = ov >> 2, hh = ov & 3; w = rk_w + (long)(hh * 64 + wi) * 1024; bias = rk_b[hh * 64 + wi]; }
  else if (ov < 260) { int q2 = ov - 256; w = rs_w + (long)q2 * 1024; bias = rs_b[q2]; }
  else if (ov < 264) { int q2 = ov - 260; w = fg_w + (long)q2 * 1024; bias = fg_b[q2]; }
  else if (ov < 276) { int q2 = ov - 264, m = q2 >> 2, hh = q2 & 3; w = rm_w + (long)(hh * 3 + m) * 1024; bias = rm_b[hh * 3 + m]; }
  else if (ov < 340) { int q2 = ov - 276; w = wk_w + (long)q2 * 1024; bias = wk_b[q2]; }
  else if (ov == 340){ w = ws_w; bias = ws_b[0]; }
  else if (ov < 405) { int q2 = ov - 341; w = ev_w + (long)q2 * 1024; bias = ev_b[q2]; }
  else if (ov < 469) { int q2 = ov - 405; w = wv_w + (long)q2 * 1024; bias = wv_b[q2]; }
  else if (ov == 469){ w = ag_w; bias = ag_b[0]; }
  else               { w = wg_w; bias = wg_b[0]; }
  if (wv == 0 && lane < 16) pbias[rsel] = bias;
  const unsigned short* Xg = (const unsigned short*)(ws + OFF_XBF);
  const unsigned short* PW = (const unsigned short*)(ws + OFF_PW);
  f32x4 acc0 = (f32x4){0.f, 0.f, 0.f, 0.f};
  f32x4 acc1 = (f32x4){0.f, 0.f, 0.f, 0.f};
#pragma unroll
  for (int kt = 0; kt < 8; ++kt) {
    int k = wv * 256 + kofs + 32 * kt;   // 0..1023
    bf16x8 bfr;
    if (BF) {
      bfr = *(const bf16x8*)&PW[(long)ov * 1024 + k];
    } else {
      float4 v0 = *(const float4*)(w + k);
      float4 v1 = *(const float4*)(w + k + 4);
      bfr[0] = (short)f2bf(v0.x); bfr[1] = (short)f2bf(v0.y);
      bfr[2] = (short)f2bf(v0.z); bfr[3] = (short)f2bf(v0.w);
      bfr[4] = (short)f2bf(v1.x); bfr[5] = (short)f2bf(v1.y);
      bfr[6] = (short)f2bf(v1.z); bfr[7] = (short)f2bf(v1.w);
    }
    bf16x8 a0 = *(const bf16x8*)&Xg[(long)rsel * 1800 + 768 + k];
    bf16x8 a1 = *(const bf16x8*)&Xg[(long)(16 + rsel) * 1800 + 768 + k];
    acc0 = __builtin_amdgcn_mfma_f32_16x16x32_bf16(a0, bfr, acc0, 0, 0, 0);
    acc1 = __builtin_amdgcn_mfma_f32_16x16x32_bf16(a1, bfr, acc1, 0, 0, 0);
  }
#pragma unroll
  for (int jj = 0; jj < 4; ++jj) {
    int b0 = (lane >> 4) * 4 + jj;
    pacc[wv][b0 * 16 + rsel] = acc0[jj];
    pacc[wv][(b0 + 16) * 16 + rsel] = acc1[jj];
  }
  __syncthreads();
  for (int idx = tid; idx < 512; idx += 256) {
    int b = idx >> 4, ol = idx & 15;
    int o2 = blockIdx.x * 16 + ol;
    if (o2 < 471) {
      float s = pacc[0][idx] + pacc[1][idx] + pacc[2][idx] + pacc[3][idx];
      ws[OFF_PROJ + (long)b * 512 + o2] = s + pbias[ol];
    }
  }
}

// ===== shuffle reductions ==================================================
__device__ __forceinline__ float red128_max(float v, float* red, int tid) {
#pragma unroll
  for (int off = 32; off; off >>= 1) v = fmaxf(v, __shfl_xor(v, off));
  if (tid < 128 && (tid & 63) == 0) red[tid >> 6] = v;
  __syncthreads();
  float r = fmaxf(red[0], red[1]);
  __syncthreads();
  return r;
}
__device__ __forceinline__ float red128_sum(float v, float* red, int tid) {
#pragma unroll
  for (int off = 32; off; off >>= 1) v += __shfl_xor(v, off);
  if (tid < 128 && (tid & 63) == 0) red[tid >> 6] = v;
  __syncthreads();
  float r = red[0] + red[1];
  __syncthreads();
  return r;
}

// ===== memAB<RBW> (r22 logic; optional rv bf16 history) ====================
constexpr int SMEMF = 28744;   // floats (114,976 B)
template <int RBW>
__global__ __launch_bounds__(256) void memAB_kernel(
    int t, float* __restrict__ ws, const float* __restrict__ emb) {
  extern __shared__ float sm[];
  float* mem_s = sm;               // [128][65]  8320
  float* lk_s  = sm + 8320;        // [128][129] 16512
  float* red   = sm + 24832;       // 8
  float* wwl   = sm + 24840;       // 128
  float* pl    = sm + 24968;       // 128
  float* kwl   = sm + 25096;       // 64
  float* knl   = sm + 25160;       // 64
  float* dl    = sm + 25224;       // 64
  float* kl    = sm + 25288;       // 256
  float* rwold = sm + 25544;       // 512
  float* rwnew = sm + 26056;       // 512
  float* fpart = sm + 26568;       // 1024
  float* bpart = sm + 27592;       // 1024
  float* su    = sm + 28616;       // 128
  int b = blockIdx.x, tid = threadIdx.x;
  int n = tid & 127, half = tid >> 7, lane = tid & 63;
  const float* pj = ws + OFF_PROJ + b * 512;
  float* u    = ws + OFF_U  + b * 128;
  float* wwp  = ws + OFF_WW + b * 128;
  float* pp   = ws + OFF_P  + b * 128;
  float* rwp  = ws + OFF_RW + b * 512;
  float* memp = ws + OFF_MEM + (long)b * 8192;
  float* lk   = ws + OFF_LINKS + (long)b * 16384;

  for (int i = tid; i < 8192; i += 256) mem_s[(i >> 6) * 65 + (i & 63)] = memp[i];
  for (int i = tid; i < 16384; i += 256) lk_s[(i >> 7) * 129 + (i & 127)] = lk[i];

  float uu = 0.f;
  if (half == 0) {
    float fg0 = sigm(pj[260]), fg1 = sigm(pj[261]), fg2 = sigm(pj[262]), fg3 = sigm(pj[263]);
    float r0 = rwp[n * 4], r1 = rwp[n * 4 + 1], r2 = rwp[n * 4 + 2], r3 = rwp[n * 4 + 3];
    rwold[n * 4] = r0; rwold[n * 4 + 1] = r1; rwold[n * 4 + 2] = r2; rwold[n * 4 + 3] = r3;
    float psi = expf(logf(1.f - fg0 * r0) + logf(1.f - fg1 * r1) +
                     logf(1.f - fg2 * r2) + logf(1.f - fg3 * r3));
    float u0 = u[n], wwo = wwp[n];
    uu = (u0 + wwo - u0 * wwo) * psi;
    u[n] = uu;
  }
  if (tid < 64) {
    kwl[tid] = pj[276 + tid];
    dl[tid] = sigm(pj[405 + tid]) - sigm(pj[341 + tid]);  // writev - erase
  }
  if (tid >= 128 && tid < 192) {
    int q = tid - 128;
#pragma unroll
    for (int h = 0; h < 4; ++h) kl[q * 4 + h] = pj[q * 4 + h];
  }
  __syncthreads();
  float kn2 = 0.f;
#pragma unroll
  for (int w = 0; w < 64; ++w) kn2 += kwl[w] * kwl[w];
  float kn = sqrtf(kn2);
  if (tid < 64) knl[tid] = kwl[tid] / kn;

  float v = uu;
  if (half == 0) {
#pragma unroll
    for (int k = 2; k <= 64; k <<= 1) {
#pragma unroll
      for (int j = k >> 1; j > 0; j >>= 1) {
        float other = __shfl_xor(v, j);
        bool up = ((n & k) == 0);
        bool high = (n & j) != 0;
        float mn = fminf(v, other), mx2 = fmaxf(v, other);
        v = (high == up) ? mx2 : mn;
      }
    }
    su[n] = v;
  }
  __syncthreads();
  if (half == 0) {
    float other = su[n ^ 64];
    v = ((n & 64) != 0) ? fmaxf(v, other) : fminf(v, other);
#pragma unroll
    for (int j = 32; j > 0; j >>= 1) {
      float other2 = __shfl_xor(v, j);
      bool high = (n & j) != 0;
      v = high ? fmaxf(v, other2) : fminf(v, other2);
    }
  }
  float lgv = 0.f;
  if (half == 0) {
    lgv = logf(v);
#pragma unroll
    for (int d = 1; d < 64; d <<= 1) {
      float t2 = __shfl_up(lgv, d);
      lgv = (lane >= d) ? lgv + t2 : lgv;
    }
  }
  if (tid == 63) red[0] = lgv;
  __syncthreads();
  if (half == 0 && (tid >> 6) == 1) lgv += red[0];
  __syncthreads();
  float mrow[64];
  float score = -3.4e38f, e = 0.f, wwn = 0.f, a_n = 0.f;
  if (half == 0) {
    a_n = (1.f - v) * expf(lgv - logf(v));
    float sq = 0.f;
#pragma unroll
    for (int w = 0; w < 64; ++w) { float m = mem_s[n * 65 + w]; mrow[w] = m; sq += m * m; }
    float den = sqrtf(sq) + EPSF;
#pragma unroll
    for (int w = 0; w < 64; ++w) mrow[w] = mrow[w] / den;
    float dot = 0.f;
#pragma unroll
    for (int w = 0; w < 64; ++w) dot += mrow[w] * knl[w];
    score = dot * oneplus_(pj[340]);
  }
  float mx = red128_max(score, red, tid);
  e = (half == 0) ? expf(score - mx) : 0.f;
  float esum = red128_sum(e, red, tid);
  if (half == 0) {
    float cw = e / esum;
    float ag = sigm(pj[469]), wg = sigm(pj[470]);
    wwn = wg * (ag * a_n + (1.f - ag) * cw);
    wwp[n] = wwn; wwl[n] = wwn;
  }
  float sumww = red128_sum((half == 0) ? wwn : 0.f, red, tid);
  if (half == 0) {
    float pn = (1.f - sumww) * pp[n] + wwn;
    pp[n] = pn; pl[n] = pn;
  }
  __syncthreads();
  if (half == 0) {
#pragma unroll
    for (int w = 0; w < 64; ++w) mem_s[n * 65 + w] = mrow[w] + wwn * dl[w];
  }
  {
    float wn = wwl[n], pcol = pl[n];
    int base = half * 64;
    for (int q = 0; q < 64; ++q) {
      int k2 = base + q;
      float lv = lk_s[k2 * 129 + n] * (1.f - (wwl[k2] + wn)) + wwl[k2] * pcol;
      lk_s[k2 * 129 + n] = (k2 == n) ? 0.f : lv;
    }
  }
  __syncthreads();

  if (half == 0) {
    float sq = 0.f;
#pragma unroll
    for (int w = 0; w < 64; ++w) { float m = mem_s[n * 65 + w]; mrow[w] = m; sq += m * m; }
    float den2 = sqrtf(sq) + EPSF;
#pragma unroll
    for (int w = 0; w < 64; ++w) { mrow[w] = mrow[w] / den2; mem_s[n * 65 + w] = mrow[w]; }
  }
  __syncthreads();
  float cr_[4];
#pragma unroll
  for (int h = 0; h < 4; ++h) {
    float s3 = 0.f;
#pragma unroll
    for (int w = 0; w < 64; ++w) { float kv = kl[w * 4 + h]; s3 += kv * kv; }
    float knh = sqrtf(s3);
    float sc = -3.4e38f;
    if (half == 0) {
      float d2 = 0.f;
#pragma unroll
      for (int w = 0; w < 64; ++w) d2 += mrow[w] * (kl[w * 4 + h] / knh);
      sc = d2 * oneplus_(pj[256 + h]);
    }
    float mxh = red128_max(sc, red, tid);
    float eh = (half == 0) ? expf(sc - mxh) : 0.f;
    float ehs = red128_sum(eh, red, tid);
    cr_[h] = eh / ehs;
  }
  {
    float f0 = 0, f1 = 0, f2 = 0, f3 = 0, b0 = 0, b1 = 0, b2 = 0, b3 = 0;
    int base = half * 64;
    for (int q = 0; q < 64; ++q) {
      int jj = base + q;
      float lrow = lk_s[n * 129 + jj];
      float lcol = lk_s[jj * 129 + n];
      float q0 = rwold[jj * 4], q1 = rwold[jj * 4 + 1], q2 = rwold[jj * 4 + 2], q3 = rwold[jj * 4 + 3];
      f0 += lrow * q0; f1 += lrow * q1; f2 += lrow * q2; f3 += lrow * q3;
      b0 += lcol * q0; b1 += lcol * q1; b2 += lcol * q2; b3 += lcol * q3;
    }
    int o = half * 512 + n * 4;
    fpart[o] = f0; fpart[o + 1] = f1; fpart[o + 2] = f2; fpart[o + 3] = f3;
    bpart[o] = b0; bpart[o + 1] = b1; bpart[o + 2] = b2; bpart[o + 3] = b3;
  }
  __syncthreads();
  if (half == 0) {
#pragma unroll
    for (int h = 0; h < 4; ++h) {
      float fv = fpart[n * 4 + h] + fpart[512 + n * 4 + h];
      float bv = bpart[n * 4 + h] + bpart[512 + n * 4 + h];
      float m0 = pj[264 + h], m1 = pj[264 + 4 + h], m2 = pj[264 + 8 + h];
      float mm = fmaxf(m0, fmaxf(m1, m2));
      float e0 = expf(m0 - mm), e1 = expf(m1 - mm), e2 = expf(m2 - mm);
      float inv = 1.f / (e0 + e1 + e2);
      float rwv = (e0 * inv) * bv + (e1 * inv) * cr_[h] + (e2 * inv) * fv;
      rwp[n * 4 + h] = rwv;
      rwnew[n * 4 + h] = rwv;
    }
  }
  __syncthreads();
  for (int i = tid; i < 8192; i += 256) memp[i] = mem_s[(i >> 6) * 65 + (i & 63)];
  for (int i = tid; i < 16384; i += 256) lk[i] = lk_s[(i >> 7) * 129 + (i & 127)];
  unsigned short* Xg = (unsigned short*)(ws + OFF_XBF);
  {
    int w2 = tid & 63, which = tid >> 6;
    float rv = 0.f;
    for (int jj = 0; jj < 128; ++jj) rv += mem_s[jj * 65 + w2] * rwnew[jj * 4 + which];
    ws[OFF_RV + (long)(t + 1) * 8192 + b * 256 + w2 * 4 + which] = rv;
    unsigned short rb = f2bf(rv);
    Xg[(long)b * 1800 + 512 + w2 * 4 + which] = rb;
    if (RBW) {
      unsigned short* RB = (unsigned short*)(ws + OFF_RVBF);
      RB[(long)(t + 1) * 8192 + b * 256 + w2 * 4 + which] = rb;
    }
  }
  if (t + 1 < TN) {
    int nsrc = ((const int*)(ws + OFF_SRC))[(t + 1) * 32 + b];
    const float* eb = emb + (long)nsrc * 512;
    for (int i = tid; i < 512; i += 256) Xg[(long)b * 1800 + i] = f2bf(eb[i]);
  }
}

// ===== out_gemm_mfma<BF,ABF> ===============================================
template <int BF, int ABF>
__global__ __launch_bounds__(512) void out_gemm_mfma(
    const float* __restrict__ ws, const float* __restrict__ Why_w,
    const float* __restrict__ Why_b, const float* __restrict__ Wry_w,
    float* __restrict__ out) {
  __shared__ unsigned short As[256 * 40];
  __shared__ unsigned short Bs[128 * 40];
  const float* Hp  = ws + OFF_H + 32768;   // [2048][1024]
  const float* RVp = ws + OFF_RV + 8192;   // [2048][256]
  const unsigned short* OW = (const unsigned short*)(ws + OFF_OW);
  const unsigned short* HB16 = (const unsigned short*)(ws + OFF_HBF) + 32768;
  const unsigned short* RB16 = (const unsigned short*)(ws + OFF_RVBF) + 8192;
  int tid = threadIdx.x;
  int wv = tid >> 6, lane = tid & 63;
  int wr = wv >> 1, wc = wv & 1;
  int col0 = blockIdx.x * 128, row0 = blockIdx.y * 256;
  f32x4 acc[4][4];
#pragma unroll
  for (int i = 0; i < 4; ++i)
#pragma unroll
    for (int j = 0; j < 4; ++j) acc[i][j] = (f32x4){0.f, 0.f, 0.f, 0.f};

  for (int kt = 0; kt < 40; ++kt) {
    int k0 = kt * 32;
    __syncthreads();
    {
      int r = tid >> 1, kh = tid & 1;
      int gk = k0 + kh * 16;
      long grow = row0 + r;
      if (ABF) {
        const unsigned short* srcb = (gk < 1024) ? (HB16 + grow * 1024 + gk)
                                                 : (RB16 + grow * 256 + (gk - 1024));
        uint4 p0 = *(const uint4*)(srcb);
        uint4 p1 = *(const uint4*)(srcb + 8);
        unsigned short* d = &As[r * 40 + kh * 16];
        *(uint4*)d = p0;
        *(uint4*)(d + 8) = p1;
      } else {
        const float* src = (gk < 1024) ? (Hp + grow * 1024 + gk)
                                       : (RVp + grow * 256 + (gk - 1024));
        float4 v0 = *(const float4*)(src);
        float4 v1 = *(const float4*)(src + 4);
        float4 v2 = *(const float4*)(src + 8);
        float4 v3 = *(const float4*)(src + 12);
        unsigned short* d = &As[r * 40 + kh * 16];
        d[0] = f2bf(v0.x);  d[1] = f2bf(v0.y);  d[2] = f2bf(v0.z);  d[3] = f2bf(v0.w);
        d[4] = f2bf(v1.x);  d[5] = f2bf(v1.y);  d[6] = f2bf(v1.z);  d[7] = f2bf(v1.w);
        d[8] = f2bf(v2.x);  d[9] = f2bf(v2.y);  d[10] = f2bf(v2.z); d[11] = f2bf(v2.w);
        d[12] = f2bf(v3.x); d[13] = f2bf(v3.y); d[14] = f2bf(v3.z); d[15] = f2bf(v3.w);
      }
    }
    {
      int r = tid >> 2, ks = (tid & 3) * 8;
      int gk = k0 + ks;
      long wrow = col0 + r;
      if (BF) {
        *(uint4*)&Bs[r * 40 + ks] = *(const uint4*)&OW[wrow * 1280 + gk];
      } else {
        const float* src = (gk < 1024) ? (Why_w + wrow * 1024 + gk)
                                       : (Wry_w + wrow * 256 + (gk - 1024));
        float4 v0 = *(const float4*)(src);
        float4 v1 = *(const float4*)(src + 4);
        unsigned short* d = &Bs[r * 40 + ks];
        d[0] = f2bf(v0.x); d[1] = f2bf(v0.y); d[2] = f2bf(v0.z); d[3] = f2bf(v0.w);
        d[4] = f2bf(v1.x); d[5] = f2bf(v1.y); d[6] = f2bf(v1.z); d[7] = f2bf(v1.w);
      }
    }
    __syncthreads();
    bf16x8 afr[4], bfr[4];
    int kofs = (lane >> 4) * 8;
    int rsel = lane & 15;
#pragma unroll
    for (int mt = 0; mt < 4; ++mt)
      afr[mt] = *(const bf16x8*)&As[(wr * 64 + mt * 16 + rsel) * 40 + kofs];
#pragma unroll
    for (int nt = 0; nt < 4; ++nt)
      bfr[nt] = *(const bf16x8*)&Bs[(wc * 64 + nt * 16 + rsel) * 40 + kofs];
#pragma unroll
    for (int mt = 0; mt < 4; ++mt)
#pragma unroll
      for (int nt = 0; nt < 4; ++nt)
        acc[mt][nt] = __builtin_amdgcn_mfma_f32_16x16x32_bf16(afr[mt], bfr[nt], acc[mt][nt], 0, 0, 0);
  }
  int crow = (lane >> 4) * 4, ccol = lane & 15;
#pragma unroll
  for (int nt = 0; nt < 4; ++nt) {
    int gcol = col0 + wc * 64 + nt * 16 + ccol;
    float bias = Why_b[gcol];
#pragma unroll
    for (int mt = 0; mt < 4; ++mt) {
      long grow = row0 + wr * 64 + mt * 16 + crow;
#pragma unroll
      for (int j = 0; j < 4; ++j) {
        out[(grow + j) * 16000 + gcol] = acc[mt][nt][j] + bias;
      }
    }
  }
}

extern "C" void kernel_launch(void* const* d_in, const int* in_sizes, int n_in,
                              void* d_out, int out_size, void* d_ws, size_t ws_size,
                              hipStream_t stream) {
  const void* src_raw = d_in[0];
  const float* emb   = (const float*)d_in[1];
  const float* W_ih  = (const float*)d_in[2];
  const float* W_hh  = (const float*)d_in[3];
  const float* b_ih  = (const float*)d_in[4];
  const float* b_hh  = (const float*)d_in[5];
  const float* rk_w  = (const float*)d_in[6];
  const float* rk_b  = (const float*)d_in[7];
  const float* rs_w  = (const float*)d_in[8];
  const float* rs_b  = (const float*)d_in[9];
  const float* fg_w  = (const float*)d_in[10];
  const float* fg_b  = (const float*)d_in[11];
  const float* rm_w  = (const float*)d_in[12];
  const float* rm_b  = (const float*)d_in[13];
  const float* wk_w  = (const float*)d_in[14];
  const float* wk_b  = (const float*)d_in[15];
  const float* ws_w  = (const float*)d_in[16];
  const float* ws_b  = (const float*)d_in[17];
  const float* ev_w  = (const float*)d_in[18];
  const float* ev_b  = (const float*)d_in[19];
  const float* wv_w  = (const float*)d_in[20];
  const float* wv_b  = (const float*)d_in[21];
  const float* ag_w  = (const float*)d_in[22];
  const float* ag_b  = (const float*)d_in[23];
  const float* wg_w  = (const float*)d_in[24];
  const float* wg_b  = (const float*)d_in[25];
  const float* Why_w = (const float*)d_in[26];
  const float* Why_b = (const float*)d_in[27];
  const float* Wry_w = (const float*)d_in[28];
  float* ws = (float*)d_ws;
  float* out = (float*)d_out;

  const bool t2 = (ws_size >= (size_t)WS_NEED2 * sizeof(float));
  const bool t1 = !t2 && (ws_size >= (size_t)WS_NEED1 * sizeof(float));
  src_decode<<<1, 256, 0, stream>>>(src_raw, ws);
  init_kernel<<<512, 256, 0, stream>>>(ws, emb);
  if (t1 || t2) {
    wconv_gates<<<1024, 256, 0, stream>>>(W_ih, W_hh, ws);
    wconv_proj<<<471, 256, 0, stream>>>(ws, rk_w, rs_w, fg_w, rm_w, wk_w, ws_w,
                                        ev_w, wv_w, ag_w, wg_w);
    wconv_out<<<2048, 256, 0, stream>>>(Why_w, Wry_w, ws);
  }
  const size_t gsm_bytes = (size_t)GSMF * sizeof(float);
  const size_t sm_bytes = (size_t)SMEMF * sizeof(float);
  for (int t = 0; t < TN; ++t) {
    if (t2)      gates_mfma<1, 1><<<256, 256, gsm_bytes, stream>>>(t, W_ih, W_hh, b_ih, b_hh, ws);
    else if (t1) gates_mfma<1, 0><<<256, 256, gsm_bytes, stream>>>(t, W_ih, W_hh, b_ih, b_hh, ws);
    else         gates_mfma<0, 0><<<256, 256, gsm_bytes, stream>>>(t, W_ih, W_hh, b_ih, b_hh, ws);
    if (t1 || t2) proj_mfma<1><<<30, 256, 0, stream>>>(t, ws, rk_w, rk_b, rs_w, rs_b, fg_w, fg_b,
                                                       rm_w, rm_b, wk_w, wk_b, ws_w, ws_b,
                                                       ev_w, ev_b, wv_w, wv_b, ag_w, ag_b, wg_w, wg_b);
    else          proj_mfma<0><<<30, 256, 0, stream>>>(t, ws, rk_w, rk_b, rs_w, rs_b, fg_w, fg_b,
                                                       rm_w, rm_b, wk_w, wk_b, ws_w, ws_b,
                                                       ev_w, ev_b, wv_w, wv_b, ag_w, ag_b, wg_w, wg_b);
    if (t2) memAB_kernel<1><<<32, 256, sm_bytes, stream>>>(t, ws, emb);
    else    memAB_kernel<0><<<32, 256, sm_bytes, stream>>>(t, ws, emb);
  }
  if (t2)      out_gemm_mfma<1, 1><<<dim3(125, 8), 512, 0, stream>>>(ws, Why_w, Why_b, Wry_w, out);
  else if (t1) out_gemm_mfma<1, 0><<<dim3(125, 8), 512, 0, stream>>>(ws, Why_w, Why_b, Wry_w, out);
  else         out_gemm_mfma<0, 0><<<dim3(125, 8), 512, 0, stream>>>(ws, Why_w, Why_b, Wry_w, out);
}